// Round 3
// baseline (531.680 us; speedup 1.0000x reference)
//
#include <hip/hip_runtime.h>
#include <hip/hip_bf16.h>

#define K3   40
#define CIN  32
#define DIN  35
#define CO   64
#define BN_EPS 1e-5f

// ---------------------------------------------------------------------------
// Output buffer is FLOAT32 (reference returns f32 tensors; harness spec:
// "bfloat16 -> __hip_bfloat16*, else float*"). Layout: n_p[M*3] | y[M*64] | n_o[1].
// ---------------------------------------------------------------------------

// Kernel 0: zero stats accumulators (ws is poisoned 0xAA) and write n_o.
__global__ void k_init(float* __restrict__ stats,
                       float* __restrict__ out_no, int M)
{
  int t = threadIdx.x;
  if (t < 512) stats[t] = 0.f;
  if (t == 0) out_no[0] = (float)M;
}

// ---------------------------------------------------------------------------
// Kernel 1: gather feat, branch GEMMs (k=10/20/40), running max per (m,c),
// and global sum / sumsq per (branch, channel).
// One wave (64 threads) per m, 4 m per block, grid-stride over m.
// Thread = output channel c. Weight columns held in registers.
// feat LDS layout per row: [x0..x31, rel0, rel1, rel2, pad] (36 floats).
// ---------------------------------------------------------------------------
__global__ void __launch_bounds__(256) k_branch(
    const float* __restrict__ p, const float* __restrict__ x,
    const int* __restrict__ fps, const int* __restrict__ knn,
    const float* __restrict__ w1, const float* __restrict__ w2,
    const float* __restrict__ w3,
    float* __restrict__ hmax1, float* __restrict__ hmax2,
    float* __restrict__ hmax3,
    float* __restrict__ stats, int M)
{
  __shared__ __align__(16) float feat[4][K3][36];
  __shared__ int sidx[4][K3];

  const int sub  = threadIdx.x >> 6;
  const int lane = threadIdx.x & 63;
  const int c    = lane;

  // weight columns in registers, in feat order (x first, rel last)
  float w1c[DIN], w2c[DIN], w3c[DIN];
#pragma unroll
  for (int j = 0; j < CIN; j++) {
    w1c[j] = w1[(3 + j) * CO + c];
    w2c[j] = w2[(3 + j) * CO + c];
    w3c[j] = w3[(3 + j) * CO + c];
  }
#pragma unroll
  for (int d = 0; d < 3; d++) {
    w1c[CIN + d] = w1[d * CO + c];
    w2c[CIN + d] = w2[d * CO + c];
    w3c[CIN + d] = w3[d * CO + c];
  }

  float s1b0 = 0.f, s1b1 = 0.f, s1b2 = 0.f;
  float s2b0 = 0.f, s2b1 = 0.f, s2b2 = 0.f;

  for (int mb = blockIdx.x * 4; mb < M; mb += gridDim.x * 4) {
    const int m = mb + sub;
    const bool act = (m < M);

    if (act && lane < K3) sidx[sub][lane] = knn[m * K3 + lane];
    __syncthreads();

    if (act) {
      // x gather: 8 float4-chunks per row, 8 rows per pass, 5 passes
      const int q = lane & 7;
#pragma unroll
      for (int pass = 0; pass < 5; pass++) {
        int row = pass * 8 + (lane >> 3);
        int gi  = sidx[sub][row];
        ((float4*)&feat[sub][row][0])[q] = ((const float4*)x)[gi * 8 + q];
      }
      // relative xyz
      int fi = fps[m];
      float cx = p[fi * 3 + 0], cy = p[fi * 3 + 1], cz = p[fi * 3 + 2];
      if (lane < K3) {
        int gi = sidx[sub][lane];
        feat[sub][lane][32] = p[gi * 3 + 0] - cx;
        feat[sub][lane][33] = p[gi * 3 + 1] - cy;
        feat[sub][lane][34] = p[gi * 3 + 2] - cz;
      }
    }
    __syncthreads();

    if (act) {
      float mx1 = -3.4e38f, mx2 = -3.4e38f, mx3 = -3.4e38f;

      // k in [0,10): all three branches
      for (int k = 0; k < 10; k++) {
        const float4* fr = (const float4*)&feat[sub][k][0];
        float h1 = 0.f, h2 = 0.f, h3 = 0.f;
#pragma unroll
        for (int i4 = 0; i4 < 8; i4++) {
          float4 f = fr[i4];
          h1 = fmaf(f.x, w1c[4*i4+0], h1); h1 = fmaf(f.y, w1c[4*i4+1], h1);
          h1 = fmaf(f.z, w1c[4*i4+2], h1); h1 = fmaf(f.w, w1c[4*i4+3], h1);
          h2 = fmaf(f.x, w2c[4*i4+0], h2); h2 = fmaf(f.y, w2c[4*i4+1], h2);
          h2 = fmaf(f.z, w2c[4*i4+2], h2); h2 = fmaf(f.w, w2c[4*i4+3], h2);
          h3 = fmaf(f.x, w3c[4*i4+0], h3); h3 = fmaf(f.y, w3c[4*i4+1], h3);
          h3 = fmaf(f.z, w3c[4*i4+2], h3); h3 = fmaf(f.w, w3c[4*i4+3], h3);
        }
        float4 f8 = fr[8];
        h1 = fmaf(f8.x, w1c[32], h1); h1 = fmaf(f8.y, w1c[33], h1); h1 = fmaf(f8.z, w1c[34], h1);
        h2 = fmaf(f8.x, w2c[32], h2); h2 = fmaf(f8.y, w2c[33], h2); h2 = fmaf(f8.z, w2c[34], h2);
        h3 = fmaf(f8.x, w3c[32], h3); h3 = fmaf(f8.y, w3c[33], h3); h3 = fmaf(f8.z, w3c[34], h3);
        s1b0 += h1; s2b0 += h1 * h1; mx1 = fmaxf(mx1, h1);
        s1b1 += h2; s2b1 += h2 * h2; mx2 = fmaxf(mx2, h2);
        s1b2 += h3; s2b2 += h3 * h3; mx3 = fmaxf(mx3, h3);
      }
      // k in [10,20): branches 2,3
      for (int k = 10; k < 20; k++) {
        const float4* fr = (const float4*)&feat[sub][k][0];
        float h2 = 0.f, h3 = 0.f;
#pragma unroll
        for (int i4 = 0; i4 < 8; i4++) {
          float4 f = fr[i4];
          h2 = fmaf(f.x, w2c[4*i4+0], h2); h2 = fmaf(f.y, w2c[4*i4+1], h2);
          h2 = fmaf(f.z, w2c[4*i4+2], h2); h2 = fmaf(f.w, w2c[4*i4+3], h2);
          h3 = fmaf(f.x, w3c[4*i4+0], h3); h3 = fmaf(f.y, w3c[4*i4+1], h3);
          h3 = fmaf(f.z, w3c[4*i4+2], h3); h3 = fmaf(f.w, w3c[4*i4+3], h3);
        }
        float4 f8 = fr[8];
        h2 = fmaf(f8.x, w2c[32], h2); h2 = fmaf(f8.y, w2c[33], h2); h2 = fmaf(f8.z, w2c[34], h2);
        h3 = fmaf(f8.x, w3c[32], h3); h3 = fmaf(f8.y, w3c[33], h3); h3 = fmaf(f8.z, w3c[34], h3);
        s1b1 += h2; s2b1 += h2 * h2; mx2 = fmaxf(mx2, h2);
        s1b2 += h3; s2b2 += h3 * h3; mx3 = fmaxf(mx3, h3);
      }
      // k in [20,40): branch 3 only
      for (int k = 20; k < 40; k++) {
        const float4* fr = (const float4*)&feat[sub][k][0];
        float h3 = 0.f;
#pragma unroll
        for (int i4 = 0; i4 < 8; i4++) {
          float4 f = fr[i4];
          h3 = fmaf(f.x, w3c[4*i4+0], h3); h3 = fmaf(f.y, w3c[4*i4+1], h3);
          h3 = fmaf(f.z, w3c[4*i4+2], h3); h3 = fmaf(f.w, w3c[4*i4+3], h3);
        }
        float4 f8 = fr[8];
        h3 = fmaf(f8.x, w3c[32], h3); h3 = fmaf(f8.y, w3c[33], h3); h3 = fmaf(f8.z, w3c[34], h3);
        s1b2 += h3; s2b2 += h3 * h3; mx3 = fmaxf(mx3, h3);
      }

      hmax1[(size_t)m * CO + c] = mx1;
      hmax2[(size_t)m * CO + c] = mx2;
      hmax3[(size_t)m * CO + c] = mx3;
    }
    __syncthreads();
  }

  // block reduction of stats across the 4 sub-waves, then atomics
  float* red = (float*)feat;  // reuse LDS
  red[(sub * 6 + 0) * 64 + c] = s1b0;
  red[(sub * 6 + 1) * 64 + c] = s1b1;
  red[(sub * 6 + 2) * 64 + c] = s1b2;
  red[(sub * 6 + 3) * 64 + c] = s2b0;
  red[(sub * 6 + 4) * 64 + c] = s2b1;
  red[(sub * 6 + 5) * 64 + c] = s2b2;
  __syncthreads();
  for (int f = threadIdx.x; f < 384; f += 256) {
    int isS2 = (f >= 192) ? 1 : 0;
    int r = f - 192 * isS2;           // r = b*64 + c
    float acc = 0.f;
#pragma unroll
    for (int s = 0; s < 4; s++) acc += red[(s * 6 + isS2 * 3) * 64 + r];
    atomicAdd(&stats[f], acc);
  }
}

// ---------------------------------------------------------------------------
// Kernel 2: finalize branch BN affine params. stats[0..191]=sum, [192..383]=sumsq
// bnp[0..191]=scale (b*64+c), bnp[192..383]=shift
// ---------------------------------------------------------------------------
__global__ void k_bn_branch(const float* __restrict__ stats,
                            const float* __restrict__ g1, const float* __restrict__ g2,
                            const float* __restrict__ g3,
                            const float* __restrict__ be1, const float* __restrict__ be2,
                            const float* __restrict__ be3,
                            float* __restrict__ bnp, int M)
{
  int t = threadIdx.x;
  if (t >= 192) return;
  int b = t >> 6, c = t & 63;
  float cnt = (float)M * (float)(10 << b);
  float mu  = stats[t] / cnt;
  float var = stats[192 + t] / cnt - mu * mu;
  const float* g  = (b == 0) ? g1 : ((b == 1) ? g2 : g3);
  const float* be = (b == 0) ? be1 : ((b == 1) ? be2 : be3);
  float sc = g[c] * rsqrtf(var + BN_EPS);
  bnp[t] = sc;
  bnp[192 + t] = be[c] - mu * sc;
}

// ---------------------------------------------------------------------------
// Kernel 3: ycat = relu(BN(hmax)) per branch; z = ycat @ w + b (f32, written
// into the output y-slot; k_out finishes BN+ReLU in place); z stats;
// also writes n_p. One wave per m, 4 m per block. w staged in LDS.
// ---------------------------------------------------------------------------
__global__ void __launch_bounds__(256) k_fuse(
    const float* __restrict__ hmax1, const float* __restrict__ hmax2,
    const float* __restrict__ hmax3,
    const float* __restrict__ bnp, const float* __restrict__ w,
    const float* __restrict__ bias,
    const float* __restrict__ p, const int* __restrict__ fps,
    float* __restrict__ zout, float* __restrict__ stats,
    float* __restrict__ out_np, int M)
{
  __shared__ float wl[192 * 64];   // 48 KB
  __shared__ float ylds[4][192];
  const int sub = threadIdx.x >> 6;
  const int c   = threadIdx.x & 63;

  for (int i = threadIdx.x; i < 192 * 64; i += 256) wl[i] = w[i];
  __syncthreads();

  float s1 = 0.f, s2 = 0.f;

  for (int mb = blockIdx.x * 4; mb < M; mb += gridDim.x * 4) {
    const int m = mb + sub;
    const bool act = (m < M);
    if (act) {
      float v1 = fmaf(hmax1[(size_t)m * 64 + c], bnp[c],       bnp[192 + c]);
      float v2 = fmaf(hmax2[(size_t)m * 64 + c], bnp[64 + c],  bnp[192 + 64 + c]);
      float v3 = fmaf(hmax3[(size_t)m * 64 + c], bnp[128 + c], bnp[192 + 128 + c]);
      ylds[sub][c]       = fmaxf(v1, 0.f);
      ylds[sub][64 + c]  = fmaxf(v2, 0.f);
      ylds[sub][128 + c] = fmaxf(v3, 0.f);
    }
    __syncthreads();
    if (act) {
      float acc = bias[c];
#pragma unroll 8
      for (int j = 0; j < 192; j++) acc = fmaf(ylds[sub][j], wl[j * 64 + c], acc);
      zout[(size_t)m * 64 + c] = acc;
      s1 += acc; s2 += acc * acc;
      if (c < 3) {
        int fi = fps[m];
        out_np[(size_t)m * 3 + c] = p[fi * 3 + c];
      }
    }
    __syncthreads();
  }

  float* red = (float*)ylds;
  red[(sub * 2 + 0) * 64 + c] = s1;
  red[(sub * 2 + 1) * 64 + c] = s2;
  __syncthreads();
  if (sub == 0) {
    float a1 = 0.f, a2 = 0.f;
#pragma unroll
    for (int s = 0; s < 4; s++) {
      a1 += red[(s * 2 + 0) * 64 + c];
      a2 += red[(s * 2 + 1) * 64 + c];
    }
    atomicAdd(&stats[384 + c], a1);
    atomicAdd(&stats[448 + c], a2);
  }
}

// ---------------------------------------------------------------------------
// Kernel 4: finalize final BN params -> bnp[384..447]=scale, [448..511]=shift
// ---------------------------------------------------------------------------
__global__ void k_bn_final(const float* __restrict__ stats,
                           const float* __restrict__ g, const float* __restrict__ be,
                           float* __restrict__ bnp, int M)
{
  int c = threadIdx.x;
  if (c >= 64) return;
  float mu  = stats[384 + c] / (float)M;
  float var = stats[448 + c] / (float)M - mu * mu;
  float sc = g[c] * rsqrtf(var + BN_EPS);
  bnp[384 + c] = sc;
  bnp[448 + c] = be[c] - mu * sc;
}

// ---------------------------------------------------------------------------
// Kernel 5: y = relu(BN(z)) in-place on the output y-slot (f32); n_o again.
// ---------------------------------------------------------------------------
__global__ void k_out(float* __restrict__ y,
                      const float* __restrict__ bnp,
                      float* __restrict__ out_no, int M)
{
  int tid = blockIdx.x * blockDim.x + threadIdx.x;
  int total = M * 64;
  if (tid < total) {
    int c = tid & 63;
    float v = fmaf(y[tid], bnp[384 + c], bnp[448 + c]);
    y[tid] = fmaxf(v, 0.f);
  }
  if (tid == 0) out_no[0] = (float)M;
}

extern "C" void kernel_launch(void* const* d_in, const int* in_sizes, int n_in,
                              void* d_out, int out_size, void* d_ws, size_t ws_size,
                              hipStream_t stream) {
  const float* p   = (const float*)d_in[0];
  const float* x   = (const float*)d_in[1];
  const int*   fps = (const int*)d_in[3];
  const int*   knn = (const int*)d_in[4];
  const float* w1  = (const float*)d_in[5];
  const float* w2  = (const float*)d_in[6];
  const float* w3  = (const float*)d_in[7];
  const float* w   = (const float*)d_in[8];
  const float* b   = (const float*)d_in[9];
  const float* g1  = (const float*)d_in[10];
  const float* g2  = (const float*)d_in[11];
  const float* g3  = (const float*)d_in[12];
  const float* g   = (const float*)d_in[13];
  const float* be1 = (const float*)d_in[14];
  const float* be2 = (const float*)d_in[15];
  const float* be3 = (const float*)d_in[16];
  const float* be  = (const float*)d_in[17];

  const int M = in_sizes[3];

  float* ws    = (float*)d_ws;
  float* hmax1 = ws;
  float* hmax2 = hmax1 + (size_t)M * 64;
  float* hmax3 = hmax2 + (size_t)M * 64;
  float* stats = hmax3 + (size_t)M * 64;   // 512 floats
  float* bnp   = stats + 512;              // 512 floats

  float* out    = (float*)d_out;
  float* out_np = out;                       // [0, 3M)
  float* out_y  = out + (size_t)3 * M;       // [3M, 67M)
  float* out_no = out + (size_t)67 * M;      // [67M]

  k_init<<<1, 512, 0, stream>>>(stats, out_no, M);
  k_branch<<<1024, 256, 0, stream>>>(p, x, fps, knn, w1, w2, w3,
                                     hmax1, hmax2, hmax3, stats, M);
  k_bn_branch<<<1, 256, 0, stream>>>(stats, g1, g2, g3, be1, be2, be3, bnp, M);
  k_fuse<<<1024, 256, 0, stream>>>(hmax1, hmax2, hmax3, bnp, w, b, p, fps,
                                   out_y, stats, out_np, M);
  k_bn_final<<<1, 64, 0, stream>>>(stats, g, be, bnp, M);
  int total = M * 64;
  k_out<<<(total + 255) / 256, 256, 0, stream>>>(out_y, bnp, out_no, M);
}

// Round 4
// 261.358 us; speedup vs baseline: 2.0343x; 2.0343x over previous
//
#include <hip/hip_runtime.h>
#include <hip/hip_bf16.h>

#define K3   40
#define CO   64
#define GM   16      // m per group (= MFMA tile rows)
#define CK   20      // k per LDS chunk
#define SROW 72      // shorts per feat row in LDS (64 data + 8 pad -> conflict-free)
#define FS   200     // shorts per ycat row in LDS (192 data + 8 pad)
#define BN_EPS 1e-5f

typedef __attribute__((ext_vector_type(8))) short short8;
typedef __attribute__((ext_vector_type(4))) float f32x4;

static __device__ __forceinline__ short f2bf(float f) {
  union { __hip_bfloat16 b; short s; } u; u.b = __float2bfloat16(f); return u.s;
}
static __device__ __forceinline__ unsigned pk2(float a, float b) {
  union { __hip_bfloat16 b; unsigned short s; } ua, ub;
  ua.b = __float2bfloat16(a); ub.b = __float2bfloat16(b);
  return (unsigned)ua.s | ((unsigned)ub.s << 16);
}

// ---------------------------------------------------------------------------
// Output buffer is FLOAT32. Layout: n_p[M*3] | y[M*64] | n_o[1].
// ---------------------------------------------------------------------------

__global__ void k_init(float* __restrict__ stats, float* __restrict__ out_no, int M)
{
  int t = threadIdx.x;
  if (t < 512) stats[t] = 0.f;
  if (t == 0) out_no[0] = (float)M;
}

// ---------------------------------------------------------------------------
// Kernel 1 (MFMA): per 16-m group, stage feat (bf16, d0..31=x, d32..34=rel,
// d35..63=0) into LDS in two 20-k chunks; each of 4 waves owns one 16-wide
// c-tile and runs 2 chained k-step MFMAs per live branch per k. Running max
// per (m,c) -> hmax; s1/s2 per (branch,c) in registers -> shuffle -> atomics.
// ---------------------------------------------------------------------------
__global__ void __launch_bounds__(256) k_branch(
    const float* __restrict__ p, const float* __restrict__ x,
    const int* __restrict__ fps, const int* __restrict__ knn,
    const float* __restrict__ w1, const float* __restrict__ w2,
    const float* __restrict__ w3,
    float* __restrict__ hmax1, float* __restrict__ hmax2,
    float* __restrict__ hmax3,
    float* __restrict__ stats, int M)
{
  __shared__ __align__(16) short abuf[CK * GM * SROW];   // 46080 B

  const int tid  = threadIdx.x;
  const int wv   = tid >> 6;
  const int lane = tid & 63;
  const int q    = lane >> 4;    // quad
  const int nn   = lane & 15;    // A-row (m_local) and B-col within tile
  const int cg   = wv * 16 + nn; // this lane's output channel

  // B fragments: lane holds w[k=q*8+j + s*32][cg], permuted to LDS d-order:
  // lds d<32 -> w row 3+d (x part); d in [32,35) -> w row d-32 (rel); else 0.
  short8 bw1[2], bw2[2], bw3[2];
#pragma unroll
  for (int s = 0; s < 2; ++s) {
#pragma unroll
    for (int j = 0; j < 8; ++j) {
      int d = s * 32 + q * 8 + j;
      int row = (d < 32) ? (3 + d) : ((d < 35) ? (d - 32) : -1);
      bw1[s][j] = f2bf(row >= 0 ? w1[row * CO + cg] : 0.f);
      bw2[s][j] = f2bf(row >= 0 ? w2[row * CO + cg] : 0.f);
      bw3[s][j] = f2bf(row >= 0 ? w3[row * CO + cg] : 0.f);
    }
  }

  float s1b0 = 0.f, s1b1 = 0.f, s1b2 = 0.f;
  float s2b0 = 0.f, s2b1 = 0.f, s2b2 = 0.f;

  const int ngrp = M / GM;   // M=60000 -> 3750 (exact)
  for (int grp = blockIdx.x; grp < ngrp; grp += gridDim.x) {
    const int base = grp * GM;
    float mx1[4], mx2[4], mx3[4];
#pragma unroll
    for (int r = 0; r < 4; ++r) { mx1[r] = -3.4e38f; mx2[r] = -3.4e38f; mx3[r] = -3.4e38f; }

    for (int ch = 0; ch < 2; ++ch) {
      __syncthreads();   // abuf free from previous chunk's MFMAs
      // ---- stage chunk: 320 rows, bf16 ----
      for (int r = tid; r < CK * GM; r += 256) {
        int kl = r >> 4;
        int ml = r & 15;
        int m  = base + ml;
        int k  = ch * CK + kl;
        int gi = knn[m * K3 + k];
        int fi = fps[m];
        const float4* xr = (const float4*)(x + (size_t)gi * 32);
        float4 x0 = xr[0], x1 = xr[1], x2 = xr[2], x3 = xr[3];
        float4 x4 = xr[4], x5 = xr[5], x6 = xr[6], x7 = xr[7];
        float r0 = p[gi * 3 + 0] - p[fi * 3 + 0];
        float r1 = p[gi * 3 + 1] - p[fi * 3 + 1];
        float r2 = p[gi * 3 + 2] - p[fi * 3 + 2];
        uint4 A0 = make_uint4(pk2(x0.x, x0.y), pk2(x0.z, x0.w), pk2(x1.x, x1.y), pk2(x1.z, x1.w));
        uint4 A1 = make_uint4(pk2(x2.x, x2.y), pk2(x2.z, x2.w), pk2(x3.x, x3.y), pk2(x3.z, x3.w));
        uint4 A2 = make_uint4(pk2(x4.x, x4.y), pk2(x4.z, x4.w), pk2(x5.x, x5.y), pk2(x5.z, x5.w));
        uint4 A3 = make_uint4(pk2(x6.x, x6.y), pk2(x6.z, x6.w), pk2(x7.x, x7.y), pk2(x7.z, x7.w));
        uint4 A4 = make_uint4(pk2(r0, r1), pk2(r2, 0.f), 0u, 0u);
        uint4 Z0 = make_uint4(0u, 0u, 0u, 0u);
        uint4* dst = (uint4*)&abuf[r * SROW];
        dst[0] = A0; dst[1] = A1; dst[2] = A2; dst[3] = A3;
        dst[4] = A4; dst[5] = Z0; dst[6] = Z0; dst[7] = Z0;
      }
      __syncthreads();
      // ---- MFMA over this chunk ----
      for (int kl = 0; kl < CK; ++kl) {
        int kg = ch * CK + kl;
        const short* ar = &abuf[(kl * GM + nn) * SROW + q * 8];
        short8 a0 = *(const short8*)ar;
        short8 a1 = *(const short8*)(ar + 32);
        f32x4 zz = {0.f, 0.f, 0.f, 0.f};
        f32x4 h3 = __builtin_amdgcn_mfma_f32_16x16x32_bf16(a0, bw3[0], zz, 0, 0, 0);
        h3 = __builtin_amdgcn_mfma_f32_16x16x32_bf16(a1, bw3[1], h3, 0, 0, 0);
#pragma unroll
        for (int r = 0; r < 4; ++r) {
          float h = h3[r];
          mx3[r] = fmaxf(mx3[r], h); s1b2 += h; s2b2 = fmaf(h, h, s2b2);
        }
        if (kg < 20) {
          f32x4 h2 = __builtin_amdgcn_mfma_f32_16x16x32_bf16(a0, bw2[0], zz, 0, 0, 0);
          h2 = __builtin_amdgcn_mfma_f32_16x16x32_bf16(a1, bw2[1], h2, 0, 0, 0);
#pragma unroll
          for (int r = 0; r < 4; ++r) {
            float h = h2[r];
            mx2[r] = fmaxf(mx2[r], h); s1b1 += h; s2b1 = fmaf(h, h, s2b1);
          }
          if (kg < 10) {
            f32x4 h1 = __builtin_amdgcn_mfma_f32_16x16x32_bf16(a0, bw1[0], zz, 0, 0, 0);
            h1 = __builtin_amdgcn_mfma_f32_16x16x32_bf16(a1, bw1[1], h1, 0, 0, 0);
#pragma unroll
            for (int r = 0; r < 4; ++r) {
              float h = h1[r];
              mx1[r] = fmaxf(mx1[r], h); s1b0 += h; s2b0 = fmaf(h, h, s2b0);
            }
          }
        }
      }
    }
    // ---- write hmax (C layout: m = base + q*4 + r, c = cg) ----
#pragma unroll
    for (int r = 0; r < 4; ++r) {
      int m = base + q * 4 + r;
      hmax1[(size_t)m * CO + cg] = mx1[r];
      hmax2[(size_t)m * CO + cg] = mx2[r];
      hmax3[(size_t)m * CO + cg] = mx3[r];
    }
  }

  // ---- stats: reduce across quads (same c), then one atomic per (c,stat) ----
  {
    float v;
    v = s1b0; v += __shfl_xor(v, 16); v += __shfl_xor(v, 32);
    if (q == 0) atomicAdd(&stats[0 * 64 + cg], v);
    v = s1b1; v += __shfl_xor(v, 16); v += __shfl_xor(v, 32);
    if (q == 0) atomicAdd(&stats[1 * 64 + cg], v);
    v = s1b2; v += __shfl_xor(v, 16); v += __shfl_xor(v, 32);
    if (q == 0) atomicAdd(&stats[2 * 64 + cg], v);
    v = s2b0; v += __shfl_xor(v, 16); v += __shfl_xor(v, 32);
    if (q == 0) atomicAdd(&stats[192 + 0 * 64 + cg], v);
    v = s2b1; v += __shfl_xor(v, 16); v += __shfl_xor(v, 32);
    if (q == 0) atomicAdd(&stats[192 + 1 * 64 + cg], v);
    v = s2b2; v += __shfl_xor(v, 16); v += __shfl_xor(v, 32);
    if (q == 0) atomicAdd(&stats[192 + 2 * 64 + cg], v);
  }
}

// ---------------------------------------------------------------------------
// Kernel 2: branch BN affines. stats[0..191]=sum, [192..383]=sumsq.
// bnp[0..191]=scale, [192..383]=shift.
// ---------------------------------------------------------------------------
__global__ void k_bn_branch(const float* __restrict__ stats,
                            const float* __restrict__ g1, const float* __restrict__ g2,
                            const float* __restrict__ g3,
                            const float* __restrict__ be1, const float* __restrict__ be2,
                            const float* __restrict__ be3,
                            float* __restrict__ bnp, int M)
{
  int t = threadIdx.x;
  if (t >= 192) return;
  int b = t >> 6, c = t & 63;
  float cnt = (float)M * (float)(10 << b);
  float mu  = stats[t] / cnt;
  float var = stats[192 + t] / cnt - mu * mu;
  const float* g  = (b == 0) ? g1 : ((b == 1) ? g2 : g3);
  const float* be = (b == 0) ? be1 : ((b == 1) ? be2 : be3);
  float sc = g[c] * rsqrtf(var + BN_EPS);
  bnp[t] = sc;
  bnp[192 + t] = be[c] - mu * sc;
}

// ---------------------------------------------------------------------------
// Kernel 3 (MFMA): ycat = relu(BN(hmax)) staged bf16 in LDS; z = ycat@w + b
// via 6 accumulating MFMAs; z -> out_y (f32, finished in place by k_out);
// z stats in registers; n_p written here too.
// ---------------------------------------------------------------------------
__global__ void __launch_bounds__(256) k_fuse(
    const float* __restrict__ hmax1, const float* __restrict__ hmax2,
    const float* __restrict__ hmax3,
    const float* __restrict__ bnp, const float* __restrict__ w,
    const float* __restrict__ bias,
    const float* __restrict__ p, const int* __restrict__ fps,
    float* __restrict__ zout, float* __restrict__ stats,
    float* __restrict__ out_np, int M)
{
  __shared__ __align__(16) short ybuf[GM * FS];   // 6400 B

  const int tid  = threadIdx.x;
  const int wv   = tid >> 6;
  const int lane = tid & 63;
  const int q    = lane >> 4;
  const int nn   = lane & 15;
  const int cg   = wv * 16 + nn;

  short8 bw[6];
#pragma unroll
  for (int s = 0; s < 6; ++s)
#pragma unroll
    for (int j = 0; j < 8; ++j)
      bw[s][j] = f2bf(w[(s * 32 + q * 8 + j) * CO + cg]);

  const float bia = bias[cg];
  float s1 = 0.f, s2 = 0.f;

  const int ml_s = tid >> 4;          // staging: m_local 0..15
  const int c4   = (tid & 15) * 4;    // staging: 4 channels

  const int ngrp = M / GM;
  for (int grp = blockIdx.x; grp < ngrp; grp += gridDim.x) {
    const int base = grp * GM;
    // ---- stage ycat (affine + relu + bf16) ----
#pragma unroll
    for (int b = 0; b < 3; ++b) {
      const float* hb = (b == 0) ? hmax1 : ((b == 1) ? hmax2 : hmax3);
      float4 v  = *(const float4*)&hb[(size_t)(base + ml_s) * CO + c4];
      float4 sc = *(const float4*)&bnp[b * 64 + c4];
      float4 sh = *(const float4*)&bnp[192 + b * 64 + c4];
      float y0 = fmaxf(fmaf(v.x, sc.x, sh.x), 0.f);
      float y1 = fmaxf(fmaf(v.y, sc.y, sh.y), 0.f);
      float y2 = fmaxf(fmaf(v.z, sc.z, sh.z), 0.f);
      float y3 = fmaxf(fmaf(v.w, sc.w, sh.w), 0.f);
      *(uint2*)&ybuf[ml_s * FS + b * 64 + c4] = make_uint2(pk2(y0, y1), pk2(y2, y3));
    }
    if (tid < 48) {
      int ml2 = tid / 3, d = tid - ml2 * 3;
      int fi = fps[base + ml2];
      out_np[(size_t)(base + ml2) * 3 + d] = p[fi * 3 + d];
    }
    __syncthreads();
    // ---- 6 accumulating MFMAs ----
    const short* ar = &ybuf[nn * FS + q * 8];
    f32x4 acc = {0.f, 0.f, 0.f, 0.f};
#pragma unroll
    for (int s = 0; s < 6; ++s) {
      short8 a = *(const short8*)(ar + s * 32);
      acc = __builtin_amdgcn_mfma_f32_16x16x32_bf16(a, bw[s], acc, 0, 0, 0);
    }
#pragma unroll
    for (int r = 0; r < 4; ++r) {
      float z = acc[r] + bia;
      int m = base + q * 4 + r;
      zout[(size_t)m * CO + cg] = z;
      s1 += z; s2 = fmaf(z, z, s2);
    }
    __syncthreads();   // ybuf reuse
  }

  float v;
  v = s1; v += __shfl_xor(v, 16); v += __shfl_xor(v, 32);
  if (q == 0) atomicAdd(&stats[384 + cg], v);
  v = s2; v += __shfl_xor(v, 16); v += __shfl_xor(v, 32);
  if (q == 0) atomicAdd(&stats[448 + cg], v);
}

// ---------------------------------------------------------------------------
// Kernel 4: final BN params -> bnp[384..447]=scale, [448..511]=shift
// ---------------------------------------------------------------------------
__global__ void k_bn_final(const float* __restrict__ stats,
                           const float* __restrict__ g, const float* __restrict__ be,
                           float* __restrict__ bnp, int M)
{
  int c = threadIdx.x;
  if (c >= 64) return;
  float mu  = stats[384 + c] / (float)M;
  float var = stats[448 + c] / (float)M - mu * mu;
  float sc = g[c] * rsqrtf(var + BN_EPS);
  bnp[384 + c] = sc;
  bnp[448 + c] = be[c] - mu * sc;
}

// ---------------------------------------------------------------------------
// Kernel 5: y = relu(BN(z)) in place (f32); n_o again.
// ---------------------------------------------------------------------------
__global__ void k_out(float* __restrict__ y, const float* __restrict__ bnp,
                      float* __restrict__ out_no, int M)
{
  int tid = blockIdx.x * blockDim.x + threadIdx.x;
  int total = M * 64;
  if (tid < total) {
    int c = tid & 63;
    float v = fmaf(y[tid], bnp[384 + c], bnp[448 + c]);
    y[tid] = fmaxf(v, 0.f);
  }
  if (tid == 0) out_no[0] = (float)M;
}

extern "C" void kernel_launch(void* const* d_in, const int* in_sizes, int n_in,
                              void* d_out, int out_size, void* d_ws, size_t ws_size,
                              hipStream_t stream) {
  const float* p   = (const float*)d_in[0];
  const float* x   = (const float*)d_in[1];
  const int*   fps = (const int*)d_in[3];
  const int*   knn = (const int*)d_in[4];
  const float* w1  = (const float*)d_in[5];
  const float* w2  = (const float*)d_in[6];
  const float* w3  = (const float*)d_in[7];
  const float* w   = (const float*)d_in[8];
  const float* b   = (const float*)d_in[9];
  const float* g1  = (const float*)d_in[10];
  const float* g2  = (const float*)d_in[11];
  const float* g3  = (const float*)d_in[12];
  const float* g   = (const float*)d_in[13];
  const float* be1 = (const float*)d_in[14];
  const float* be2 = (const float*)d_in[15];
  const float* be3 = (const float*)d_in[16];
  const float* be  = (const float*)d_in[17];

  const int M = in_sizes[3];

  float* ws    = (float*)d_ws;
  float* hmax1 = ws;
  float* hmax2 = hmax1 + (size_t)M * 64;
  float* hmax3 = hmax2 + (size_t)M * 64;
  float* stats = hmax3 + (size_t)M * 64;   // 512 floats
  float* bnp   = stats + 512;              // 512 floats

  float* out    = (float*)d_out;
  float* out_np = out;                       // [0, 3M)
  float* out_y  = out + (size_t)3 * M;       // [3M, 67M)
  float* out_no = out + (size_t)67 * M;      // [67M]

  k_init<<<1, 512, 0, stream>>>(stats, out_no, M);
  k_branch<<<768, 256, 0, stream>>>(p, x, fps, knn, w1, w2, w3,
                                    hmax1, hmax2, hmax3, stats, M);
  k_bn_branch<<<1, 256, 0, stream>>>(stats, g1, g2, g3, be1, be2, be3, bnp, M);
  k_fuse<<<1024, 256, 0, stream>>>(hmax1, hmax2, hmax3, bnp, w, b, p, fps,
                                   out_y, stats, out_np, M);
  k_bn_final<<<1, 64, 0, stream>>>(stats, g, be, bnp, M);
  int total = M * 64;
  k_out<<<(total + 255) / 256, 256, 0, stream>>>(out_y, bnp, out_no, M);
}